// Round 2
// baseline (6671.071 us; speedup 1.0000x reference)
//
#include <hip/hip_runtime.h>
#include <hip/hip_fp16.h>

typedef unsigned short u16;
typedef unsigned int   u32;

#define B_   32
#define T_   2048
#define C_   256
#define H_   256
#define TC_  1024
#define M_   (B_*TC_)   // 32768

using bf16x8 = __attribute__((ext_vector_type(8))) short;
using f32x4  = __attribute__((ext_vector_type(4))) float;
typedef _Float16 f16x2 __attribute__((ext_vector_type(2)));

__device__ __forceinline__ u16 f2bf(float f) {
  u32 u = __float_as_uint(f);
  u32 r = u + 0x7fffu + ((u >> 16) & 1u);
  return (u16)(r >> 16);
}
__device__ __forceinline__ float sigmf(float x) { return 1.f / (1.f + __expf(-x)); }
// tanh(x) = 1 - 2/(e^{2x}+1); exact limits at +-inf, ~1e-7 rel error
__device__ __forceinline__ float tanhfast(float x) {
  float e = __expf(2.f * x);
  return 1.f - 2.f / (e + 1.f);
}
__device__ __forceinline__ float dot2(u32 w, u32 h, float acc) {
  return __builtin_amdgcn_fdot2(__builtin_bit_cast(f16x2, w),
                                __builtin_bit_cast(f16x2, h), acc, false);
}
// sum over the 4 lanes of a quad (lane bits 0..1), result in all 4 lanes.
// quad_perm DPP adds: VALU pipe, no LDS traffic.
__device__ __forceinline__ float qsum4(float x) {
  int a = __builtin_amdgcn_update_dpp(0, __float_as_int(x), 0xB1, 0xF, 0xF, true); // xor1
  x += __int_as_float(a);
  int b = __builtin_amdgcn_update_dpp(0, __float_as_int(x), 0x4E, 0xF, 0xF, true); // xor2
  return x + __int_as_float(b);
}

// ---------------- casts ----------------
__global__ void cast_bf16_kernel(const float* __restrict__ src, u16* __restrict__ dst, int n) {
  int i = blockIdx.x * 256 + threadIdx.x;
  if (i < n) dst[i] = f2bf(src[i]);
}
__global__ void cast_f16_kernel(const float* __restrict__ src, u16* __restrict__ dst, int n) {
  int i = blockIdx.x * 256 + threadIdx.x;
  if (i < n) dst[i] = __half_as_ushort(__float2half(src[i]));
}

// ---------------- conv + bn + relu -> y bf16 (B*TC, C) ----------------
__global__ __launch_bounds__(256)
void conv_bn_kernel(const float* __restrict__ x, const float* __restrict__ cw,
                    const float* __restrict__ cb, const float* __restrict__ bng,
                    const float* __restrict__ bnb, const float* __restrict__ bnm,
                    const float* __restrict__ bnv, u16* __restrict__ ybf) {
  int c = threadIdx.x;
  int bt = blockIdx.x;                  // b*TC + t
  int t = bt & (TC_ - 1), b = bt >> 10;
  const float* xr = x + (size_t)b * T_;
  float xm1 = (t > 0) ? xr[2 * t - 1] : 0.f;
  float x0 = xr[2 * t], xp1 = xr[2 * t + 1];
  float w0 = cw[c * 3], w1 = cw[c * 3 + 1], w2 = cw[c * 3 + 2];
  float inv = bng[c] * rsqrtf(bnv[c] + 1e-5f);
  float beta = bnb[c] - bnm[c] * inv;
  float v = w0 * xm1 + w1 * x0 + w2 * xp1 + cb[c];
  v = v * inv + beta;
  v = fmaxf(v, 0.f);
  ybf[(size_t)bt * C_ + c] = f2bf(v);
}

// ---------------- projection GEMM v2: LDS-staged 128x128 tile ----------------
#define PBK 32
#define APAD 8
__global__ __launch_bounds__(256)
void proj_gemm2_kernel(const u16* __restrict__ A,
                       const u16* __restrict__ Wf, const u16* __restrict__ Wr,
                       const float* __restrict__ bf, const float* __restrict__ br,
                       float* __restrict__ outf, float* __restrict__ outr,
                       int K) {
  const u16* W = blockIdx.z ? Wr : Wf;
  const float* bias = blockIdx.z ? br : bf;
  float* out = blockIdx.z ? outr : outf;
  __shared__ u16 As[128][PBK + APAD];
  __shared__ u16 Ws[128][PBK + APAD];
  const int tid = threadIdx.x;
  const int wave = tid >> 6, lane = tid & 63;
  const int l16 = lane & 15, quad = lane >> 4;
  const int m0 = blockIdx.x * 128, n0 = blockIdx.y * 128;
  const int wm = (wave >> 1) * 64, wn = (wave & 1) * 64;
  const int srow = tid >> 2, scol = (tid & 3) * 8;
  const u16* Ag0 = A + (size_t)(m0 + srow) * K + scol;
  const u16* Ag1 = Ag0 + (size_t)64 * K;
  const u16* Wg0 = W + (size_t)(n0 + srow) * K + scol;
  const u16* Wg1 = Wg0 + (size_t)64 * K;
  f32x4 acc[4][4] = {};
  for (int k0 = 0; k0 < K; k0 += PBK) {
    *(uint4*)&As[srow][scol]      = *(const uint4*)(Ag0 + k0);
    *(uint4*)&As[srow + 64][scol] = *(const uint4*)(Ag1 + k0);
    *(uint4*)&Ws[srow][scol]      = *(const uint4*)(Wg0 + k0);
    *(uint4*)&Ws[srow + 64][scol] = *(const uint4*)(Wg1 + k0);
    __syncthreads();
    bf16x8 af[4], wf[4];
#pragma unroll
    for (int i = 0; i < 4; ++i) {
      af[i] = *(const bf16x8*)&As[wm + 16 * i + l16][quad * 8];
      wf[i] = *(const bf16x8*)&Ws[wn + 16 * i + l16][quad * 8];
    }
#pragma unroll
    for (int i = 0; i < 4; ++i)
#pragma unroll
      for (int j = 0; j < 4; ++j)
        acc[i][j] = __builtin_amdgcn_mfma_f32_16x16x32_bf16(af[i], wf[j], acc[i][j], 0, 0, 0);
    __syncthreads();
  }
  float bv[4];
#pragma unroll
  for (int j = 0; j < 4; ++j) bv[j] = bias[n0 + wn + 16 * j + l16];
#pragma unroll
  for (int i = 0; i < 4; ++i) {
    int row = m0 + wm + 16 * i + quad * 4;
#pragma unroll
    for (int j = 0; j < 4; ++j) {
      int col = n0 + wn + 16 * j + l16;
#pragma unroll
      for (int r = 0; r < 4; ++r)
        out[(size_t)(row + r) * 1024 + col] = acc[i][j][r] + bv[j];
    }
  }
}

// ---------------- LSTM scan v5: 4-wave block, VGPR-resident weights ----------------
// 256 thr = 4 waves (1/SIMD -> 512 VGPR budget). Thread (p=tid>>2, kq=tid&3)
// owns gate rows r = p + 64a + 256g (a,g in 0..3) over k-quarter kq (32 u32).
// 12 rows (a<3) weights in VGPRs (384 regs); 4 rows (a=3) streamed from LDS.
// Per step per CU: (8 h + 32 w) b128 x 4 waves = 160 LDS instrs (vs 384 in v4).
// k-quarter reduce: DPP quad_perm butterfly (VALU pipe, zero LDS).
// After reduce, lane a=kq owns hidden j = p + 64*kq completely: all 4 gates
// in-thread, c in a register, every thread stores h. One barrier per step.
#define SCAN5_LDS (131072 + 1024)   // wlds [32][256] uint4 + hbuf [2][256] u16
__global__ __launch_bounds__(256, 1)
void scan5_kernel(const float* __restrict__ pre_f, const float* __restrict__ pre_r,
                  const u32* __restrict__ whh_f, const u32* __restrict__ whh_r,
                  void* __restrict__ outp, int out_bf16) {
  extern __shared__ char smem[];
  uint4* wlds = (uint4*)smem;             // [32][256]: chunk c = g*8+i, slot tid
  u16*   hbuf = (u16*)(smem + 131072);    // [2][256] f16
  const int tid = threadIdx.x;
  const int p = tid >> 2, kq = tid & 3;
  const int chain = blockIdx.x;
  const int dir = chain & 1, b = chain >> 1;
  const float* pre = dir ? pre_r : pre_f;
  const u32* whh = dir ? whh_r : whh_f;   // f16-pair packed [1024][128]

  // ---- weight init: rows r(a,g) = p + 64a + 256g, k-quarter kq ----
  uint4 wr[12][8];                        // a<3: m = a*4+g
#pragma unroll
  for (int a = 0; a < 3; ++a)
#pragma unroll
    for (int g = 0; g < 4; ++g) {
      const u32* wp = whh + (size_t)(p + 64 * a + 256 * g) * 128 + kq * 32;
#pragma unroll
      for (int i = 0; i < 8; ++i) wr[a * 4 + g][i] = *(const uint4*)(wp + i * 4);
    }
#pragma unroll
  for (int g = 0; g < 4; ++g) {
    const u32* wp = whh + (size_t)(p + 192 + 256 * g) * 128 + kq * 32;
#pragma unroll
    for (int i = 0; i < 8; ++i) wlds[(g * 8 + i) * 256 + tid] = *(const uint4*)(wp + i * 4);
  }
  hbuf[tid] = 0u;                         // zero h buffer 0 (256 f16)
  float cst = 0.f;
  __syncthreads();

  const int j = p + 64 * kq;              // this lane's hidden unit after reduce
  for (int t = 0; t < TC_; ++t) {
    const int tt = dir ? (TC_ - 1 - t) : t;
    // pre loads for this step (consumed after ~1500cy dot loop -> latency hidden)
    const float* pr = pre + ((size_t)b * TC_ + tt) * 1024 + j;
    float pv0 = pr[0], pv1 = pr[256], pv2 = pr[512], pv3 = pr[768];

    const uint4* hq = (const uint4*)(hbuf + (t & 1) * 256) + kq * 8;
    float acc[12] = {};
    float accL[4] = {};
#pragma unroll
    for (int i = 0; i < 8; ++i) {
      uint4 h4 = hq[i];
#pragma unroll
      for (int m = 0; m < 12; ++m) {
        acc[m] = dot2(wr[m][i].x, h4.x, acc[m]);
        acc[m] = dot2(wr[m][i].y, h4.y, acc[m]);
        acc[m] = dot2(wr[m][i].z, h4.z, acc[m]);
        acc[m] = dot2(wr[m][i].w, h4.w, acc[m]);
      }
#pragma unroll
      for (int g = 0; g < 4; ++g) {
        uint4 wv = wlds[(g * 8 + i) * 256 + tid];
        accL[g] = dot2(wv.x, h4.x, accL[g]);
        accL[g] = dot2(wv.y, h4.y, accL[g]);
        accL[g] = dot2(wv.z, h4.z, accL[g]);
        accL[g] = dot2(wv.w, h4.w, accL[g]);
      }
    }
    // reduce k-quarters across the quad (VALU DPP, no LDS)
#pragma unroll
    for (int m = 0; m < 12; ++m) acc[m] = qsum4(acc[m]);
#pragma unroll
    for (int g = 0; g < 4; ++g) accL[g] = qsum4(accL[g]);
    // lane selects a = kq: gate g pre-activation for hidden j
    float pg[4];
#pragma unroll
    for (int g = 0; g < 4; ++g) {
      float v = (kq == 0) ? acc[g] : (kq == 1) ? acc[4 + g] : (kq == 2) ? acc[8 + g] : accL[g];
      pg[g] = v;
    }
    float i_ = sigmf(pg[0] + pv0);
    float f_ = sigmf(pg[1] + pv1);
    float g_ = tanhfast(pg[2] + pv2);
    float o_ = sigmf(pg[3] + pv3);
    cst = f_ * cst + i_ * g_;
    float h = o_ * tanhfast(cst);
    // stores: every thread owns one j
    hbuf[((t + 1) & 1) * 256 + j] = __half_as_ushort(__float2half(h));
    size_t oi = ((size_t)b * TC_ + tt) * 512 + (size_t)dir * 256 + j;
    if (out_bf16) ((u16*)outp)[oi] = f2bf(h);
    else          ((float*)outp)[oi] = h;
    __syncthreads();
  }
}

// ---------------- FC heads ----------------
__global__ void fc_init_kernel(const float* __restrict__ fc1_b, const float* __restrict__ fc2_b,
                               float* __restrict__ out) {
  int i = blockIdx.x * 256 + threadIdx.x;
  if (i < 3200) out[i] = fc1_b[i % 100];
  else if (i < 6080) out[i] = fc2_b[(i - 3200) % 90];
}

#define FCK 1024
#define FCSUB 64
__global__ __launch_bounds__(256)
void fc_kernel(const float* __restrict__ flat, const float* __restrict__ w1,
               const float* __restrict__ w2, float* __restrict__ out) {
  __shared__ float fs[32][FCSUB + 1];
  __shared__ float ws[192][FCSUB + 1];
  int tid = threadIdx.x;
  int tn = tid & 31, tb = tid >> 5;
  size_t k0 = (size_t)blockIdx.x * FCK;
  float acc[4][6] = {};
  for (int kc = 0; kc < FCK; kc += FCSUB) {
    __syncthreads();
    for (int idx = tid; idx < 32 * FCSUB; idx += 256) {
      int bb = idx >> 6, j = idx & 63;
      fs[bb][j] = flat[(size_t)bb * 524288 + k0 + kc + j];
    }
    for (int idx = tid; idx < 192 * FCSUB; idx += 256) {
      int n = idx >> 6, j = idx & 63;
      float v = 0.f;
      if (n < 100)      v = w1[(size_t)n * 524288 + k0 + kc + j];
      else if (n < 190) v = w2[(size_t)(n - 100) * 524288 + k0 + kc + j];
      ws[n][j] = v;
    }
    __syncthreads();
    for (int j = 0; j < FCSUB; ++j) {
      float fv[4], wv[6];
#pragma unroll
      for (int m = 0; m < 4; ++m) fv[m] = fs[tb + 8 * m][j];
#pragma unroll
      for (int mm = 0; mm < 6; ++mm) wv[mm] = ws[tn + 32 * mm][j];
#pragma unroll
      for (int m = 0; m < 4; ++m)
#pragma unroll
        for (int mm = 0; mm < 6; ++mm) acc[m][mm] = fmaf(fv[m], wv[mm], acc[m][mm]);
    }
  }
#pragma unroll
  for (int m = 0; m < 4; ++m)
#pragma unroll
    for (int mm = 0; mm < 6; ++mm) {
      int n = tn + 32 * mm, bb = tb + 8 * m;
      if (n < 190) {
        int oi = (n < 100) ? (bb * 100 + n) : (3200 + bb * 90 + (n - 100));
        atomicAdd(out + oi, acc[m][mm]);
      }
    }
}

// ---------------- launcher ----------------
extern "C" void kernel_launch(void* const* d_in, const int* in_sizes, int n_in,
                              void* d_out, int out_size, void* d_ws, size_t ws_size,
                              hipStream_t stream) {
  const float* x       = (const float*)d_in[0];
  const float* conv_w  = (const float*)d_in[1];
  const float* conv_b  = (const float*)d_in[2];
  const float* bn_g    = (const float*)d_in[3];
  const float* bn_bb   = (const float*)d_in[4];
  const float* bn_m    = (const float*)d_in[5];
  const float* bn_v    = (const float*)d_in[6];
  const float* w_ih_f0 = (const float*)d_in[7];
  const float* w_hh_f0 = (const float*)d_in[8];
  const float* b_f0    = (const float*)d_in[9];
  const float* w_ih_r0 = (const float*)d_in[10];
  const float* w_hh_r0 = (const float*)d_in[11];
  const float* b_r0    = (const float*)d_in[12];
  const float* w_ih_f1 = (const float*)d_in[13];
  const float* w_hh_f1 = (const float*)d_in[14];
  const float* b_f1    = (const float*)d_in[15];
  const float* w_ih_r1 = (const float*)d_in[16];
  const float* w_hh_r1 = (const float*)d_in[17];
  const float* b_r1    = (const float*)d_in[18];
  const float* fc1_w   = (const float*)d_in[19];
  const float* fc1_b   = (const float*)d_in[20];
  const float* fc2_w   = (const float*)d_in[21];
  const float* fc2_b   = (const float*)d_in[22];
  float* out = (float*)d_out;

  char* base = (char*)d_ws;
  size_t off = 0;
  auto carve = [&](size_t bytes) -> char* {
    char* p = base + off;
    off += (bytes + 511) & ~(size_t)511;
    return p;
  };
  u16*   ybf   = (u16*)carve((size_t)M_ * 256 * 2);
  u16*   wb_f0 = (u16*)carve((size_t)262144 * 2);
  u16*   wb_r0 = (u16*)carve((size_t)262144 * 2);
  u16*   wb_f1 = (u16*)carve((size_t)524288 * 2);
  u16*   wb_r1 = (u16*)carve((size_t)524288 * 2);
  u16*   wh_f0 = (u16*)carve((size_t)262144 * 2);
  u16*   wh_r0 = (u16*)carve((size_t)262144 * 2);
  u16*   wh_f1 = (u16*)carve((size_t)262144 * 2);
  u16*   wh_r1 = (u16*)carve((size_t)262144 * 2);
  u16*   h0cat = (u16*)carve((size_t)M_ * 512 * 2);
  float* h1cat = (float*)carve((size_t)M_ * 512 * 4);
  float* pre_f = (float*)carve((size_t)M_ * 1024 * 4);
  float* pre_r = (float*)carve((size_t)M_ * 1024 * 4);
  if (off > ws_size) return;

  hipFuncSetAttribute((const void*)scan5_kernel,
                      hipFuncAttributeMaxDynamicSharedMemorySize, SCAN5_LDS);

  cast_bf16_kernel<<<1024, 256, 0, stream>>>(w_ih_f0, wb_f0, 262144);
  cast_bf16_kernel<<<1024, 256, 0, stream>>>(w_ih_r0, wb_r0, 262144);
  cast_bf16_kernel<<<2048, 256, 0, stream>>>(w_ih_f1, wb_f1, 524288);
  cast_bf16_kernel<<<2048, 256, 0, stream>>>(w_ih_r1, wb_r1, 524288);
  cast_f16_kernel<<<1024, 256, 0, stream>>>(w_hh_f0, wh_f0, 262144);
  cast_f16_kernel<<<1024, 256, 0, stream>>>(w_hh_r0, wh_r0, 262144);
  cast_f16_kernel<<<1024, 256, 0, stream>>>(w_hh_f1, wh_f1, 262144);
  cast_f16_kernel<<<1024, 256, 0, stream>>>(w_hh_r1, wh_r1, 262144);

  conv_bn_kernel<<<M_, 256, 0, stream>>>(x, conv_w, conv_b, bn_g, bn_bb, bn_m, bn_v, ybf);

  proj_gemm2_kernel<<<dim3(256, 8, 2), 256, 0, stream>>>(
      ybf, wb_f0, wb_r0, b_f0, b_r0, pre_f, pre_r, 256);

  scan5_kernel<<<64, 256, SCAN5_LDS, stream>>>(
      pre_f, pre_r, (const u32*)wh_f0, (const u32*)wh_r0, (void*)h0cat, 1);

  proj_gemm2_kernel<<<dim3(256, 8, 2), 256, 0, stream>>>(
      h0cat, wb_f1, wb_r1, b_f1, b_r1, pre_f, pre_r, 512);

  scan5_kernel<<<64, 256, SCAN5_LDS, stream>>>(
      pre_f, pre_r, (const u32*)wh_f1, (const u32*)wh_r1, (void*)h1cat, 0);

  fc_init_kernel<<<24, 256, 0, stream>>>(fc1_b, fc2_b, out);
  fc_kernel<<<512, 256, 0, stream>>>(h1cat, fc1_w, fc2_w, out);
}

// Round 3
// 4225.710 us; speedup vs baseline: 1.5787x; 1.5787x over previous
//
#include <hip/hip_runtime.h>
#include <hip/hip_fp16.h>

typedef unsigned short u16;
typedef unsigned int   u32;

#define B_   32
#define T_   2048
#define C_   256
#define H_   256
#define TC_  1024
#define M_   (B_*TC_)   // 32768

using bf16x8 = __attribute__((ext_vector_type(8))) short;
using f32x4  = __attribute__((ext_vector_type(4))) float;
typedef _Float16 f16x2 __attribute__((ext_vector_type(2)));

__device__ __forceinline__ u16 f2bf(float f) {
  u32 u = __float_as_uint(f);
  u32 r = u + 0x7fffu + ((u >> 16) & 1u);
  return (u16)(r >> 16);
}
__device__ __forceinline__ float sigmf(float x) { return 1.f / (1.f + __expf(-x)); }
// tanh(x) = 1 - 2/(e^{2x}+1); exact limits at +-inf, ~1e-7 rel error
__device__ __forceinline__ float tanhfast(float x) {
  float e = __expf(2.f * x);
  return 1.f - 2.f / (e + 1.f);
}
__device__ __forceinline__ float dot2(u32 w, u32 h, float acc) {
  return __builtin_amdgcn_fdot2(__builtin_bit_cast(f16x2, w),
                                __builtin_bit_cast(f16x2, h), acc, false);
}
// add lane^1's value (quad_perm [1,0,3,2]); VALU pipe, no LDS traffic
__device__ __forceinline__ float qsum2(float x) {
  int a = __builtin_amdgcn_update_dpp(0, __float_as_int(x), 0xB1, 0xF, 0xF, true);
  return x + __int_as_float(a);
}

// ---------------- casts ----------------
__global__ void cast_bf16_kernel(const float* __restrict__ src, u16* __restrict__ dst, int n) {
  int i = blockIdx.x * 256 + threadIdx.x;
  if (i < n) dst[i] = f2bf(src[i]);
}
__global__ void cast_f16_kernel(const float* __restrict__ src, u16* __restrict__ dst, int n) {
  int i = blockIdx.x * 256 + threadIdx.x;
  if (i < n) dst[i] = __half_as_ushort(__float2half(src[i]));
}

// ---------------- conv + bn + relu -> y bf16 (B*TC, C) ----------------
__global__ __launch_bounds__(256)
void conv_bn_kernel(const float* __restrict__ x, const float* __restrict__ cw,
                    const float* __restrict__ cb, const float* __restrict__ bng,
                    const float* __restrict__ bnb, const float* __restrict__ bnm,
                    const float* __restrict__ bnv, u16* __restrict__ ybf) {
  int c = threadIdx.x;
  int bt = blockIdx.x;                  // b*TC + t
  int t = bt & (TC_ - 1), b = bt >> 10;
  const float* xr = x + (size_t)b * T_;
  float xm1 = (t > 0) ? xr[2 * t - 1] : 0.f;
  float x0 = xr[2 * t], xp1 = xr[2 * t + 1];
  float w0 = cw[c * 3], w1 = cw[c * 3 + 1], w2 = cw[c * 3 + 2];
  float inv = bng[c] * rsqrtf(bnv[c] + 1e-5f);
  float beta = bnb[c] - bnm[c] * inv;
  float v = w0 * xm1 + w1 * x0 + w2 * xp1 + cb[c];
  v = v * inv + beta;
  v = fmaxf(v, 0.f);
  ybf[(size_t)bt * C_ + c] = f2bf(v);
}

// ---------------- projection GEMM v2: LDS-staged 128x128 tile ----------------
#define PBK 32
#define APAD 8
__global__ __launch_bounds__(256)
void proj_gemm2_kernel(const u16* __restrict__ A,
                       const u16* __restrict__ Wf, const u16* __restrict__ Wr,
                       const float* __restrict__ bf, const float* __restrict__ br,
                       float* __restrict__ outf, float* __restrict__ outr,
                       int K) {
  const u16* W = blockIdx.z ? Wr : Wf;
  const float* bias = blockIdx.z ? br : bf;
  float* out = blockIdx.z ? outr : outf;
  __shared__ u16 As[128][PBK + APAD];
  __shared__ u16 Ws[128][PBK + APAD];
  const int tid = threadIdx.x;
  const int wave = tid >> 6, lane = tid & 63;
  const int l16 = lane & 15, quad = lane >> 4;
  const int m0 = blockIdx.x * 128, n0 = blockIdx.y * 128;
  const int wm = (wave >> 1) * 64, wn = (wave & 1) * 64;
  const int srow = tid >> 2, scol = (tid & 3) * 8;
  const u16* Ag0 = A + (size_t)(m0 + srow) * K + scol;
  const u16* Ag1 = Ag0 + (size_t)64 * K;
  const u16* Wg0 = W + (size_t)(n0 + srow) * K + scol;
  const u16* Wg1 = Wg0 + (size_t)64 * K;
  f32x4 acc[4][4] = {};
  for (int k0 = 0; k0 < K; k0 += PBK) {
    *(uint4*)&As[srow][scol]      = *(const uint4*)(Ag0 + k0);
    *(uint4*)&As[srow + 64][scol] = *(const uint4*)(Ag1 + k0);
    *(uint4*)&Ws[srow][scol]      = *(const uint4*)(Wg0 + k0);
    *(uint4*)&Ws[srow + 64][scol] = *(const uint4*)(Wg1 + k0);
    __syncthreads();
    bf16x8 af[4], wf[4];
#pragma unroll
    for (int i = 0; i < 4; ++i) {
      af[i] = *(const bf16x8*)&As[wm + 16 * i + l16][quad * 8];
      wf[i] = *(const bf16x8*)&Ws[wn + 16 * i + l16][quad * 8];
    }
#pragma unroll
    for (int i = 0; i < 4; ++i)
#pragma unroll
      for (int j = 0; j < 4; ++j)
        acc[i][j] = __builtin_amdgcn_mfma_f32_16x16x32_bf16(af[i], wf[j], acc[i][j], 0, 0, 0);
    __syncthreads();
  }
  float bv[4];
#pragma unroll
  for (int j = 0; j < 4; ++j) bv[j] = bias[n0 + wn + 16 * j + l16];
#pragma unroll
  for (int i = 0; i < 4; ++i) {
    int row = m0 + wm + 16 * i + quad * 4;
#pragma unroll
    for (int j = 0; j < 4; ++j) {
      int col = n0 + wn + 16 * j + l16;
#pragma unroll
      for (int r = 0; r < 4; ++r)
        out[(size_t)(row + r) * 1024 + col] = acc[i][j][r] + bv[j];
    }
  }
}

// ---------------- LSTM scan v6: 512 thr, 2 waves/SIMD, weights truly resident ----------------
// Thread (p=tid>>1, kh=tid&1) owns the 4 gate rows of hidden unit p
// (rows p+256g, g=0..3) over k-half kh (64 u32 each). Rows g=0..2 in VGPR
// (48 uint4 = 192 regs, fits the 256 cap of 2 waves/SIMD); row g=3 in LDS
// ([16][512] uint4 = 128 KB). Per step: 16 h-reads + 16 w-reads b128/thread.
// Pair-reduce over kh via DPP quad_perm xor1 (VALU pipe). Each thread then
// has ALL 4 gates of unit p: no gate exchange; both lanes update c
// redundantly; lane kh=0 stores out, lane kh=1 stores h. 1 barrier/step.
// h halves at 272-B stride -> disjoint banks (v5's 128-B stride was 4-way).
#define SCAN6_LDS (131072 + 1088)   // wlds [16][512] uint4 + hbuf 2 x 544 B
__global__ __launch_bounds__(512, 2)
void scan6_kernel(const float* __restrict__ pre_f, const float* __restrict__ pre_r,
                  const u32* __restrict__ whh_f, const u32* __restrict__ whh_r,
                  void* __restrict__ outp, int out_bf16) {
  extern __shared__ char smem[];
  uint4* wlds = (uint4*)smem;              // [16][512]: chunk i, slot tid
  char* hb_base = smem + 131072;           // [2][544] B: buf, then kh-half at +272
  const int tid = threadIdx.x;
  const int p = tid >> 1, kh = tid & 1;
  const int chain = blockIdx.x;
  const int dir = chain & 1, b = chain >> 1;
  const float* pre = dir ? pre_r : pre_f;
  const u32* whh = dir ? whh_r : whh_f;    // f16-pair packed [1024][128]

  // rows g=0..2 -> VGPR, row g=3 -> LDS; k-half kh = u32 cols [kh*64, kh*64+64)
  uint4 wr[48];
#pragma unroll
  for (int g = 0; g < 3; ++g) {
    const u32* wp = whh + (size_t)(p + 256 * g) * 128 + kh * 64;
#pragma unroll
    for (int i = 0; i < 16; ++i) wr[g * 16 + i] = *(const uint4*)(wp + i * 4);
  }
  {
    const u32* wp = whh + (size_t)(p + 768) * 128 + kh * 64;
#pragma unroll
    for (int i = 0; i < 16; ++i) wlds[i * 512 + tid] = *(const uint4*)(wp + i * 4);
  }
  if (tid < 272) ((u32*)hb_base)[tid] = 0u;   // zero both h buffers (1088 B)
  float cst = 0.f;
  __syncthreads();
  asm volatile("" ::: "memory");   // pin weight loads before the scan loop

  for (int t = 0; t < TC_; ++t) {
    const int tt = dir ? (TC_ - 1 - t) : t;
    // pre: kh=0 loads gates {i,f}, kh=1 loads gates {g,o} (2 floats each)
    const float* pr = pre + ((size_t)b * TC_ + tt) * 1024 + p + 512 * kh;
    float pva = pr[0], pvb = pr[256];

    const uint4* hq = (const uint4*)(hb_base + (t & 1) * 544 + kh * 272);
    float a0 = 0.f, a1 = 0.f, a2 = 0.f, a3 = 0.f;
#pragma unroll
    for (int i = 0; i < 16; ++i) {
      uint4 h4 = hq[i];
      a0 = dot2(wr[i].x, h4.x, a0);
      a0 = dot2(wr[i].y, h4.y, a0);
      a0 = dot2(wr[i].z, h4.z, a0);
      a0 = dot2(wr[i].w, h4.w, a0);
      a1 = dot2(wr[16 + i].x, h4.x, a1);
      a1 = dot2(wr[16 + i].y, h4.y, a1);
      a1 = dot2(wr[16 + i].z, h4.z, a1);
      a1 = dot2(wr[16 + i].w, h4.w, a1);
      a2 = dot2(wr[32 + i].x, h4.x, a2);
      a2 = dot2(wr[32 + i].y, h4.y, a2);
      a2 = dot2(wr[32 + i].z, h4.z, a2);
      a2 = dot2(wr[32 + i].w, h4.w, a2);
      uint4 wv = wlds[i * 512 + tid];
      a3 = dot2(wv.x, h4.x, a3);
      a3 = dot2(wv.y, h4.y, a3);
      a3 = dot2(wv.z, h4.z, a3);
      a3 = dot2(wv.w, h4.w, a3);
    }
    // add pre before the pair-reduce (each half adds its 2 gates once)
    if (kh == 0) { a0 += pva; a1 += pvb; }
    else         { a2 += pva; a3 += pvb; }
    a0 = qsum2(a0); a1 = qsum2(a1); a2 = qsum2(a2); a3 = qsum2(a3);
    float i_ = sigmf(a0);
    float f_ = sigmf(a1);
    float g_ = tanhfast(a2);
    float o_ = sigmf(a3);
    cst = f_ * cst + i_ * g_;
    float h = o_ * tanhfast(cst);
    if (kh) {
      u16* hw = (u16*)(hb_base + ((t + 1) & 1) * 544 + (p >> 7) * 272);
      hw[p & 127] = __half_as_ushort(__float2half(h));
    } else {
      size_t oi = ((size_t)b * TC_ + tt) * 512 + (size_t)dir * 256 + p;
      if (out_bf16) ((u16*)outp)[oi] = f2bf(h);
      else          ((float*)outp)[oi] = h;
    }
    __syncthreads();
  }
}

// ---------------- FC heads ----------------
__global__ void fc_init_kernel(const float* __restrict__ fc1_b, const float* __restrict__ fc2_b,
                               float* __restrict__ out) {
  int i = blockIdx.x * 256 + threadIdx.x;
  if (i < 3200) out[i] = fc1_b[i % 100];
  else if (i < 6080) out[i] = fc2_b[(i - 3200) % 90];
}

#define FCK 1024
#define FCSUB 64
__global__ __launch_bounds__(256)
void fc_kernel(const float* __restrict__ flat, const float* __restrict__ w1,
               const float* __restrict__ w2, float* __restrict__ out) {
  __shared__ float fs[32][FCSUB + 1];
  __shared__ float ws[192][FCSUB + 1];
  int tid = threadIdx.x;
  int tn = tid & 31, tb = tid >> 5;
  size_t k0 = (size_t)blockIdx.x * FCK;
  float acc[4][6] = {};
  for (int kc = 0; kc < FCK; kc += FCSUB) {
    __syncthreads();
    for (int idx = tid; idx < 32 * FCSUB; idx += 256) {
      int bb = idx >> 6, j = idx & 63;
      fs[bb][j] = flat[(size_t)bb * 524288 + k0 + kc + j];
    }
    for (int idx = tid; idx < 192 * FCSUB; idx += 256) {
      int n = idx >> 6, j = idx & 63;
      float v = 0.f;
      if (n < 100)      v = w1[(size_t)n * 524288 + k0 + kc + j];
      else if (n < 190) v = w2[(size_t)(n - 100) * 524288 + k0 + kc + j];
      ws[n][j] = v;
    }
    __syncthreads();
    for (int j = 0; j < FCSUB; ++j) {
      float fv[4], wv[6];
#pragma unroll
      for (int m = 0; m < 4; ++m) fv[m] = fs[tb + 8 * m][j];
#pragma unroll
      for (int mm = 0; mm < 6; ++mm) wv[mm] = ws[tn + 32 * mm][j];
#pragma unroll
      for (int m = 0; m < 4; ++m)
#pragma unroll
        for (int mm = 0; mm < 6; ++mm) acc[m][mm] = fmaf(fv[m], wv[mm], acc[m][mm]);
    }
  }
#pragma unroll
  for (int m = 0; m < 4; ++m)
#pragma unroll
    for (int mm = 0; mm < 6; ++mm) {
      int n = tn + 32 * mm, bb = tb + 8 * m;
      if (n < 190) {
        int oi = (n < 100) ? (bb * 100 + n) : (3200 + bb * 90 + (n - 100));
        atomicAdd(out + oi, acc[m][mm]);
      }
    }
}

// ---------------- launcher ----------------
extern "C" void kernel_launch(void* const* d_in, const int* in_sizes, int n_in,
                              void* d_out, int out_size, void* d_ws, size_t ws_size,
                              hipStream_t stream) {
  const float* x       = (const float*)d_in[0];
  const float* conv_w  = (const float*)d_in[1];
  const float* conv_b  = (const float*)d_in[2];
  const float* bn_g    = (const float*)d_in[3];
  const float* bn_bb   = (const float*)d_in[4];
  const float* bn_m    = (const float*)d_in[5];
  const float* bn_v    = (const float*)d_in[6];
  const float* w_ih_f0 = (const float*)d_in[7];
  const float* w_hh_f0 = (const float*)d_in[8];
  const float* b_f0    = (const float*)d_in[9];
  const float* w_ih_r0 = (const float*)d_in[10];
  const float* w_hh_r0 = (const float*)d_in[11];
  const float* b_r0    = (const float*)d_in[12];
  const float* w_ih_f1 = (const float*)d_in[13];
  const float* w_hh_f1 = (const float*)d_in[14];
  const float* b_f1    = (const float*)d_in[15];
  const float* w_ih_r1 = (const float*)d_in[16];
  const float* w_hh_r1 = (const float*)d_in[17];
  const float* b_r1    = (const float*)d_in[18];
  const float* fc1_w   = (const float*)d_in[19];
  const float* fc1_b   = (const float*)d_in[20];
  const float* fc2_w   = (const float*)d_in[21];
  const float* fc2_b   = (const float*)d_in[22];
  float* out = (float*)d_out;

  char* base = (char*)d_ws;
  size_t off = 0;
  auto carve = [&](size_t bytes) -> char* {
    char* p = base + off;
    off += (bytes + 511) & ~(size_t)511;
    return p;
  };
  u16*   ybf   = (u16*)carve((size_t)M_ * 256 * 2);
  u16*   wb_f0 = (u16*)carve((size_t)262144 * 2);
  u16*   wb_r0 = (u16*)carve((size_t)262144 * 2);
  u16*   wb_f1 = (u16*)carve((size_t)524288 * 2);
  u16*   wb_r1 = (u16*)carve((size_t)524288 * 2);
  u16*   wh_f0 = (u16*)carve((size_t)262144 * 2);
  u16*   wh_r0 = (u16*)carve((size_t)262144 * 2);
  u16*   wh_f1 = (u16*)carve((size_t)262144 * 2);
  u16*   wh_r1 = (u16*)carve((size_t)262144 * 2);
  u16*   h0cat = (u16*)carve((size_t)M_ * 512 * 2);
  float* h1cat = (float*)carve((size_t)M_ * 512 * 4);
  float* pre_f = (float*)carve((size_t)M_ * 1024 * 4);
  float* pre_r = (float*)carve((size_t)M_ * 1024 * 4);
  if (off > ws_size) return;

  hipFuncSetAttribute((const void*)scan6_kernel,
                      hipFuncAttributeMaxDynamicSharedMemorySize, SCAN6_LDS);

  cast_bf16_kernel<<<1024, 256, 0, stream>>>(w_ih_f0, wb_f0, 262144);
  cast_bf16_kernel<<<1024, 256, 0, stream>>>(w_ih_r0, wb_r0, 262144);
  cast_bf16_kernel<<<2048, 256, 0, stream>>>(w_ih_f1, wb_f1, 524288);
  cast_bf16_kernel<<<2048, 256, 0, stream>>>(w_ih_r1, wb_r1, 524288);
  cast_f16_kernel<<<1024, 256, 0, stream>>>(w_hh_f0, wh_f0, 262144);
  cast_f16_kernel<<<1024, 256, 0, stream>>>(w_hh_r0, wh_r0, 262144);
  cast_f16_kernel<<<1024, 256, 0, stream>>>(w_hh_f1, wh_f1, 262144);
  cast_f16_kernel<<<1024, 256, 0, stream>>>(w_hh_r1, wh_r1, 262144);

  conv_bn_kernel<<<M_, 256, 0, stream>>>(x, conv_w, conv_b, bn_g, bn_bb, bn_m, bn_v, ybf);

  proj_gemm2_kernel<<<dim3(256, 8, 2), 256, 0, stream>>>(
      ybf, wb_f0, wb_r0, b_f0, b_r0, pre_f, pre_r, 256);

  scan6_kernel<<<64, 512, SCAN6_LDS, stream>>>(
      pre_f, pre_r, (const u32*)wh_f0, (const u32*)wh_r0, (void*)h0cat, 1);

  proj_gemm2_kernel<<<dim3(256, 8, 2), 256, 0, stream>>>(
      h0cat, wb_f1, wb_r1, b_f1, b_r1, pre_f, pre_r, 512);

  scan6_kernel<<<64, 512, SCAN6_LDS, stream>>>(
      pre_f, pre_r, (const u32*)wh_f1, (const u32*)wh_r1, (void*)h1cat, 0);

  fc_init_kernel<<<24, 256, 0, stream>>>(fc1_b, fc2_b, out);
  fc_kernel<<<512, 256, 0, stream>>>(h1cat, fc1_w, fc2_w, out);
}

// Round 4
// 4184.354 us; speedup vs baseline: 1.5943x; 1.0099x over previous
//
#include <hip/hip_runtime.h>
#include <hip/hip_fp16.h>

typedef unsigned short u16;
typedef unsigned int   u32;

#define B_   32
#define T_   2048
#define C_   256
#define H_   256
#define TC_  1024
#define M_   (B_*TC_)   // 32768

using bf16x8 = __attribute__((ext_vector_type(8))) short;
using f32x4  = __attribute__((ext_vector_type(4))) float;
using u32x4  = __attribute__((ext_vector_type(4))) u32;
typedef _Float16 f16x2 __attribute__((ext_vector_type(2)));

__device__ __forceinline__ u16 f2bf(float f) {
  u32 u = __float_as_uint(f);
  u32 r = u + 0x7fffu + ((u >> 16) & 1u);
  return (u16)(r >> 16);
}
__device__ __forceinline__ float sigmf(float x) { return 1.f / (1.f + __expf(-x)); }
// tanh(x) = 1 - 2/(e^{2x}+1); exact limits at +-inf, ~1e-7 rel error
__device__ __forceinline__ float tanhfast(float x) {
  float e = __expf(2.f * x);
  return 1.f - 2.f / (e + 1.f);
}
__device__ __forceinline__ float dot2(u32 w, u32 h, float acc) {
  return __builtin_amdgcn_fdot2(__builtin_bit_cast(f16x2, w),
                                __builtin_bit_cast(f16x2, h), acc, false);
}
// add lane^1's value (quad_perm [1,0,3,2]); VALU pipe, no LDS traffic
__device__ __forceinline__ float qsum2(float x) {
  int a = __builtin_amdgcn_update_dpp(0, __float_as_int(x), 0xB1, 0xF, 0xF, true);
  return x + __int_as_float(a);
}

// ---------------- casts ----------------
__global__ void cast_bf16_kernel(const float* __restrict__ src, u16* __restrict__ dst, int n) {
  int i = blockIdx.x * 256 + threadIdx.x;
  if (i < n) dst[i] = f2bf(src[i]);
}
__global__ void cast_f16_kernel(const float* __restrict__ src, u16* __restrict__ dst, int n) {
  int i = blockIdx.x * 256 + threadIdx.x;
  if (i < n) dst[i] = __half_as_ushort(__float2half(src[i]));
}

// ---------------- conv + bn + relu -> y bf16 (B*TC, C) ----------------
__global__ __launch_bounds__(256)
void conv_bn_kernel(const float* __restrict__ x, const float* __restrict__ cw,
                    const float* __restrict__ cb, const float* __restrict__ bng,
                    const float* __restrict__ bnb, const float* __restrict__ bnm,
                    const float* __restrict__ bnv, u16* __restrict__ ybf) {
  int c = threadIdx.x;
  int bt = blockIdx.x;                  // b*TC + t
  int t = bt & (TC_ - 1), b = bt >> 10;
  const float* xr = x + (size_t)b * T_;
  float xm1 = (t > 0) ? xr[2 * t - 1] : 0.f;
  float x0 = xr[2 * t], xp1 = xr[2 * t + 1];
  float w0 = cw[c * 3], w1 = cw[c * 3 + 1], w2 = cw[c * 3 + 2];
  float inv = bng[c] * rsqrtf(bnv[c] + 1e-5f);
  float beta = bnb[c] - bnm[c] * inv;
  float v = w0 * xm1 + w1 * x0 + w2 * xp1 + cb[c];
  v = v * inv + beta;
  v = fmaxf(v, 0.f);
  ybf[(size_t)bt * C_ + c] = f2bf(v);
}

// ---------------- projection GEMM v2: LDS-staged 128x128 tile ----------------
#define PBK 32
#define APAD 8
__global__ __launch_bounds__(256)
void proj_gemm2_kernel(const u16* __restrict__ A,
                       const u16* __restrict__ Wf, const u16* __restrict__ Wr,
                       const float* __restrict__ bf, const float* __restrict__ br,
                       float* __restrict__ outf, float* __restrict__ outr,
                       int K) {
  const u16* W = blockIdx.z ? Wr : Wf;
  const float* bias = blockIdx.z ? br : bf;
  float* out = blockIdx.z ? outr : outf;
  __shared__ u16 As[128][PBK + APAD];
  __shared__ u16 Ws[128][PBK + APAD];
  const int tid = threadIdx.x;
  const int wave = tid >> 6, lane = tid & 63;
  const int l16 = lane & 15, quad = lane >> 4;
  const int m0 = blockIdx.x * 128, n0 = blockIdx.y * 128;
  const int wm = (wave >> 1) * 64, wn = (wave & 1) * 64;
  const int srow = tid >> 2, scol = (tid & 3) * 8;
  const u16* Ag0 = A + (size_t)(m0 + srow) * K + scol;
  const u16* Ag1 = Ag0 + (size_t)64 * K;
  const u16* Wg0 = W + (size_t)(n0 + srow) * K + scol;
  const u16* Wg1 = Wg0 + (size_t)64 * K;
  f32x4 acc[4][4] = {};
  for (int k0 = 0; k0 < K; k0 += PBK) {
    *(uint4*)&As[srow][scol]      = *(const uint4*)(Ag0 + k0);
    *(uint4*)&As[srow + 64][scol] = *(const uint4*)(Ag1 + k0);
    *(uint4*)&Ws[srow][scol]      = *(const uint4*)(Wg0 + k0);
    *(uint4*)&Ws[srow + 64][scol] = *(const uint4*)(Wg1 + k0);
    __syncthreads();
    bf16x8 af[4], wf[4];
#pragma unroll
    for (int i = 0; i < 4; ++i) {
      af[i] = *(const bf16x8*)&As[wm + 16 * i + l16][quad * 8];
      wf[i] = *(const bf16x8*)&Ws[wn + 16 * i + l16][quad * 8];
    }
#pragma unroll
    for (int i = 0; i < 4; ++i)
#pragma unroll
      for (int j = 0; j < 4; ++j)
        acc[i][j] = __builtin_amdgcn_mfma_f32_16x16x32_bf16(af[i], wf[j], acc[i][j], 0, 0, 0);
    __syncthreads();
  }
  float bv[4];
#pragma unroll
  for (int j = 0; j < 4; ++j) bv[j] = bias[n0 + wn + 16 * j + l16];
#pragma unroll
  for (int i = 0; i < 4; ++i) {
    int row = m0 + wm + 16 * i + quad * 4;
#pragma unroll
    for (int j = 0; j < 4; ++j) {
      int col = n0 + wn + 16 * j + l16;
#pragma unroll
      for (int r = 0; r < 4; ++r)
        out[(size_t)(row + r) * 1024 + col] = acc[i][j][r] + bv[j];
    }
  }
}

// ---------------- LSTM scan v7: v6 + forced weight residency ----------------
// Same decomposition as v6: thread (p=tid>>1, kh=tid&1) owns the 4 gate rows
// of hidden unit p over k-half kh. Rows g=0..2 (48 u32x4 = 192 VGPR) pinned
// in registers via volatile-asm opaque values (cannot be remat'd/re-loaded);
// row g=3 streamed from LDS (128 KB). amdgpu_waves_per_eu(2,2) gives the
// allocator the full 256-reg budget (LDS caps us at 1 WG/CU anyway).
// Per step per thread: 16 h-b128 + 16 w-b128 LDS reads; 64 dot2 x 4 gates...
// (512 dot2-instrs/SIMD = 1024 cyc VALU) ; DPP pair-reduce; 1 barrier.
#define SCAN7_LDS (131072 + 1088)   // wlds [16][512] uint4 + hbuf 2 x 544 B
__global__ __launch_bounds__(512)
__attribute__((amdgpu_waves_per_eu(2, 2)))
void scan7_kernel(const float* __restrict__ pre_f, const float* __restrict__ pre_r,
                  const u32* __restrict__ whh_f, const u32* __restrict__ whh_r,
                  void* __restrict__ outp, int out_bf16) {
  extern __shared__ char smem[];
  uint4* wlds = (uint4*)smem;              // [16][512]: chunk i, slot tid
  char* hb_base = smem + 131072;           // [2][544] B: buf, then kh-half at +272
  const int tid = threadIdx.x;
  const int p = tid >> 1, kh = tid & 1;
  const int chain = blockIdx.x;
  const int dir = chain & 1, b = chain >> 1;
  const float* pre = dir ? pre_r : pre_f;
  const u32* whh = dir ? whh_r : whh_f;    // f16-pair packed [1024][128]

  // rows g=0..2 -> VGPR (pinned), row g=3 -> LDS; k-half kh = cols [kh*64,+64)
  u32x4 wr[48];
#pragma unroll
  for (int g = 0; g < 3; ++g) {
    const u32* wp = whh + (size_t)(p + 256 * g) * 128 + kh * 64;
#pragma unroll
    for (int i = 0; i < 16; ++i) wr[g * 16 + i] = *(const u32x4*)(wp + i * 4);
  }
  {
    const u32* wp = whh + (size_t)(p + 768) * 128 + kh * 64;
#pragma unroll
    for (int i = 0; i < 16; ++i) wlds[i * 512 + tid] = *(const uint4*)(wp + i * 4);
  }
  // pin: opaque values must stay live in VGPRs for the whole scan loop
#pragma unroll
  for (int i = 0; i < 48; ++i) asm volatile("" : "+v"(wr[i]));
  if (tid < 272) ((u32*)hb_base)[tid] = 0u;   // zero both h buffers (1088 B)
  float cst = 0.f;
  __syncthreads();

  for (int t = 0; t < TC_; ++t) {
    const int tt = dir ? (TC_ - 1 - t) : t;
    // pre: kh=0 loads gates {i,f}, kh=1 loads gates {g,o} (2 floats each)
    const float* pr = pre + ((size_t)b * TC_ + tt) * 1024 + p + 512 * kh;
    float pva = pr[0], pvb = pr[256];

    const uint4* hq = (const uint4*)(hb_base + (t & 1) * 544 + kh * 272);
    float a0 = 0.f, a1 = 0.f, a2 = 0.f, a3 = 0.f;
#pragma unroll
    for (int i = 0; i < 16; ++i) {
      uint4 h4 = hq[i];
      a0 = dot2(wr[i][0], h4.x, a0);
      a0 = dot2(wr[i][1], h4.y, a0);
      a0 = dot2(wr[i][2], h4.z, a0);
      a0 = dot2(wr[i][3], h4.w, a0);
      a1 = dot2(wr[16 + i][0], h4.x, a1);
      a1 = dot2(wr[16 + i][1], h4.y, a1);
      a1 = dot2(wr[16 + i][2], h4.z, a1);
      a1 = dot2(wr[16 + i][3], h4.w, a1);
      a2 = dot2(wr[32 + i][0], h4.x, a2);
      a2 = dot2(wr[32 + i][1], h4.y, a2);
      a2 = dot2(wr[32 + i][2], h4.z, a2);
      a2 = dot2(wr[32 + i][3], h4.w, a2);
      uint4 wv = wlds[i * 512 + tid];
      a3 = dot2(wv.x, h4.x, a3);
      a3 = dot2(wv.y, h4.y, a3);
      a3 = dot2(wv.z, h4.z, a3);
      a3 = dot2(wv.w, h4.w, a3);
    }
    // add pre before the pair-reduce (each half adds its 2 gates once)
    if (kh == 0) { a0 += pva; a1 += pvb; }
    else         { a2 += pva; a3 += pvb; }
    a0 = qsum2(a0); a1 = qsum2(a1); a2 = qsum2(a2); a3 = qsum2(a3);
    float i_ = sigmf(a0);
    float f_ = sigmf(a1);
    float g_ = tanhfast(a2);
    float o_ = sigmf(a3);
    cst = f_ * cst + i_ * g_;
    float h = o_ * tanhfast(cst);
    if (kh) {
      u16* hw = (u16*)(hb_base + ((t + 1) & 1) * 544 + (p >> 7) * 272);
      hw[p & 127] = __half_as_ushort(__float2half(h));
    } else {
      size_t oi = ((size_t)b * TC_ + tt) * 512 + (size_t)dir * 256 + p;
      if (out_bf16) ((u16*)outp)[oi] = f2bf(h);
      else          ((float*)outp)[oi] = h;
    }
    __syncthreads();
  }
}

// ---------------- FC heads ----------------
__global__ void fc_init_kernel(const float* __restrict__ fc1_b, const float* __restrict__ fc2_b,
                               float* __restrict__ out) {
  int i = blockIdx.x * 256 + threadIdx.x;
  if (i < 3200) out[i] = fc1_b[i % 100];
  else if (i < 6080) out[i] = fc2_b[(i - 3200) % 90];
}

#define FCK 1024
#define FCSUB 64
__global__ __launch_bounds__(256)
void fc_kernel(const float* __restrict__ flat, const float* __restrict__ w1,
               const float* __restrict__ w2, float* __restrict__ out) {
  __shared__ float fs[32][FCSUB + 1];
  __shared__ float ws[192][FCSUB + 1];
  int tid = threadIdx.x;
  int tn = tid & 31, tb = tid >> 5;
  size_t k0 = (size_t)blockIdx.x * FCK;
  float acc[4][6] = {};
  for (int kc = 0; kc < FCK; kc += FCSUB) {
    __syncthreads();
    for (int idx = tid; idx < 32 * FCSUB; idx += 256) {
      int bb = idx >> 6, j = idx & 63;
      fs[bb][j] = flat[(size_t)bb * 524288 + k0 + kc + j];
    }
    for (int idx = tid; idx < 192 * FCSUB; idx += 256) {
      int n = idx >> 6, j = idx & 63;
      float v = 0.f;
      if (n < 100)      v = w1[(size_t)n * 524288 + k0 + kc + j];
      else if (n < 190) v = w2[(size_t)(n - 100) * 524288 + k0 + kc + j];
      ws[n][j] = v;
    }
    __syncthreads();
    for (int j = 0; j < FCSUB; ++j) {
      float fv[4], wv[6];
#pragma unroll
      for (int m = 0; m < 4; ++m) fv[m] = fs[tb + 8 * m][j];
#pragma unroll
      for (int mm = 0; mm < 6; ++mm) wv[mm] = ws[tn + 32 * mm][j];
#pragma unroll
      for (int m = 0; m < 4; ++m)
#pragma unroll
        for (int mm = 0; mm < 6; ++mm) acc[m][mm] = fmaf(fv[m], wv[mm], acc[m][mm]);
    }
  }
#pragma unroll
  for (int m = 0; m < 4; ++m)
#pragma unroll
    for (int mm = 0; mm < 6; ++mm) {
      int n = tn + 32 * mm, bb = tb + 8 * m;
      if (n < 190) {
        int oi = (n < 100) ? (bb * 100 + n) : (3200 + bb * 90 + (n - 100));
        atomicAdd(out + oi, acc[m][mm]);
      }
    }
}

// ---------------- launcher ----------------
extern "C" void kernel_launch(void* const* d_in, const int* in_sizes, int n_in,
                              void* d_out, int out_size, void* d_ws, size_t ws_size,
                              hipStream_t stream) {
  const float* x       = (const float*)d_in[0];
  const float* conv_w  = (const float*)d_in[1];
  const float* conv_b  = (const float*)d_in[2];
  const float* bn_g    = (const float*)d_in[3];
  const float* bn_bb   = (const float*)d_in[4];
  const float* bn_m    = (const float*)d_in[5];
  const float* bn_v    = (const float*)d_in[6];
  const float* w_ih_f0 = (const float*)d_in[7];
  const float* w_hh_f0 = (const float*)d_in[8];
  const float* b_f0    = (const float*)d_in[9];
  const float* w_ih_r0 = (const float*)d_in[10];
  const float* w_hh_r0 = (const float*)d_in[11];
  const float* b_r0    = (const float*)d_in[12];
  const float* w_ih_f1 = (const float*)d_in[13];
  const float* w_hh_f1 = (const float*)d_in[14];
  const float* b_f1    = (const float*)d_in[15];
  const float* w_ih_r1 = (const float*)d_in[16];
  const float* w_hh_r1 = (const float*)d_in[17];
  const float* b_r1    = (const float*)d_in[18];
  const float* fc1_w   = (const float*)d_in[19];
  const float* fc1_b   = (const float*)d_in[20];
  const float* fc2_w   = (const float*)d_in[21];
  const float* fc2_b   = (const float*)d_in[22];
  float* out = (float*)d_out;

  char* base = (char*)d_ws;
  size_t off = 0;
  auto carve = [&](size_t bytes) -> char* {
    char* p = base + off;
    off += (bytes + 511) & ~(size_t)511;
    return p;
  };
  u16*   ybf   = (u16*)carve((size_t)M_ * 256 * 2);
  u16*   wb_f0 = (u16*)carve((size_t)262144 * 2);
  u16*   wb_r0 = (u16*)carve((size_t)262144 * 2);
  u16*   wb_f1 = (u16*)carve((size_t)524288 * 2);
  u16*   wb_r1 = (u16*)carve((size_t)524288 * 2);
  u16*   wh_f0 = (u16*)carve((size_t)262144 * 2);
  u16*   wh_r0 = (u16*)carve((size_t)262144 * 2);
  u16*   wh_f1 = (u16*)carve((size_t)262144 * 2);
  u16*   wh_r1 = (u16*)carve((size_t)262144 * 2);
  u16*   h0cat = (u16*)carve((size_t)M_ * 512 * 2);
  float* h1cat = (float*)carve((size_t)M_ * 512 * 4);
  float* pre_f = (float*)carve((size_t)M_ * 1024 * 4);
  float* pre_r = (float*)carve((size_t)M_ * 1024 * 4);
  if (off > ws_size) return;

  hipFuncSetAttribute((const void*)scan7_kernel,
                      hipFuncAttributeMaxDynamicSharedMemorySize, SCAN7_LDS);

  cast_bf16_kernel<<<1024, 256, 0, stream>>>(w_ih_f0, wb_f0, 262144);
  cast_bf16_kernel<<<1024, 256, 0, stream>>>(w_ih_r0, wb_r0, 262144);
  cast_bf16_kernel<<<2048, 256, 0, stream>>>(w_ih_f1, wb_f1, 524288);
  cast_bf16_kernel<<<2048, 256, 0, stream>>>(w_ih_r1, wb_r1, 524288);
  cast_f16_kernel<<<1024, 256, 0, stream>>>(w_hh_f0, wh_f0, 262144);
  cast_f16_kernel<<<1024, 256, 0, stream>>>(w_hh_r0, wh_r0, 262144);
  cast_f16_kernel<<<1024, 256, 0, stream>>>(w_hh_f1, wh_f1, 262144);
  cast_f16_kernel<<<1024, 256, 0, stream>>>(w_hh_r1, wh_r1, 262144);

  conv_bn_kernel<<<M_, 256, 0, stream>>>(x, conv_w, conv_b, bn_g, bn_bb, bn_m, bn_v, ybf);

  proj_gemm2_kernel<<<dim3(256, 8, 2), 256, 0, stream>>>(
      ybf, wb_f0, wb_r0, b_f0, b_r0, pre_f, pre_r, 256);

  scan7_kernel<<<64, 512, SCAN7_LDS, stream>>>(
      pre_f, pre_r, (const u32*)wh_f0, (const u32*)wh_r0, (void*)h0cat, 1);

  proj_gemm2_kernel<<<dim3(256, 8, 2), 256, 0, stream>>>(
      h0cat, wb_f1, wb_r1, b_f1, b_r1, pre_f, pre_r, 512);

  scan7_kernel<<<64, 512, SCAN7_LDS, stream>>>(
      pre_f, pre_r, (const u32*)wh_f1, (const u32*)wh_r1, (void*)h1cat, 0);

  fc_init_kernel<<<24, 256, 0, stream>>>(fc1_b, fc2_b, out);
  fc_kernel<<<512, 256, 0, stream>>>(h1cat, fc1_w, fc2_w, out);
}